// Round 2
// baseline (33619.601 us; speedup 1.0000x reference)
//
#include <hip/hip_runtime.h>

// ============================================================================
// 2-layer LSTM (B=256, T=1024, H=512, in=1) + linear head. fp32 in/out.
//
// R2: persistent kernel, 192 WGs x 512 thr, layer-pipelined (L0: 64 WGs,
// L1: 128 WGs), one grid barrier per step.
//  - h exchange: agent-scope relaxed atomic stores (write through to LLC) +
//    agent-scope relaxed atomic 8B loads (sc0 sc1: bypass stale L1/L2, read
//    LLC). NO full-cache invalidate fence (R1's buffer_inv nuked L2 every
//    step -> everything became LLC-latency misses).
//  - Full-step register prefetch of A-fragments (u64[16][2] arrays, ~190
//    VGPRs) so LLC latency is paid once per step, not once per kt.
//  - Hierarchical barrier: per-XCD (HW_REG_XCC_ID) arrival counters + release
//    flags on separate 128B lines, WG0 leader is master. 8x less contention.
//  - Output: 8-way-split partials buffer + epilogue reduce kernel (was 64-way
//    fp32 atomic contention per element).
// Weights LDS-resident fp16 (MFMA B-fragment order). h carried as fp16 hi +
// (lo*1024). MFMA f32_16x16x32_f16, fp32 accum, fp32 cell state in regs.
// ============================================================================

typedef _Float16 f16;
typedef _Float16 f16x8 __attribute__((ext_vector_type(8)));
typedef float f32x4 __attribute__((ext_vector_type(4)));
typedef unsigned long long u64;

#define NB 256
#define NT_ 1024
#define NH 512
#define NGRID 192
// s_getreg imm: ID=20 (HW_REG_XCC_ID), offset 0, size 32
#define XCC_GETREG_IMM (20 | (31 << 11))

__device__ __forceinline__ float sigm(float x)  { return 1.0f / (1.0f + __expf(-x)); }
__device__ __forceinline__ float tanhx(float x) { return 2.0f / (1.0f + __expf(-2.0f * x)) - 1.0f; }

// 8B coherent load: bypasses L1/L2 (sc0 sc1), reads the LLC coherence point.
__device__ __forceinline__ u64 ld8(const f16* p) {
  return __hip_atomic_load((const u64*)p, __ATOMIC_RELAXED, __HIP_MEMORY_SCOPE_AGENT);
}
union FragU { u64 u[2]; f16x8 v; };

// ---------------------------------------------------------------------------
__global__ void prep_xT(const float* __restrict__ inp, float* __restrict__ xT) {
  int g = blockIdx.x * 256 + threadIdx.x;
  int t = g >> 8, b = g & 255;
  xT[t * NB + b] = inp[b * NT_ + t];
}

// ---------------------------------------------------------------------------
// fp32 weights -> fp16, pre-tiled into MFMA B-fragment order (see R1 notes).
__global__ void prep_w(const float* __restrict__ Wh0,
                       const float* __restrict__ Wx1,
                       const float* __restrict__ Wh1,
                       f16* __restrict__ dst) {
  int g = blockIdx.x * 256 + threadIdx.x;
  int mat = g >> 20;
  int r = g & 0xFFFFF;
  int j  = r & 7;
  int ln = (r >> 3) & 63;
  int cl = ln & 15, qd = ln >> 4;
  int k, gcol; size_t di; const float* W;
  if (mat == 0) {
    int nt = (r >> 9) & 3;
    int kt = (r >> 11) & 15;
    int hb = (r >> 15) & 31;
    W = Wh0;
    gcol = nt * 512 + hb * 16 + cl;
    k = kt * 32 + qd * 8 + j;
    di = (size_t)hb * 32768 + ((size_t)(kt * 4 + nt) * 64 + ln) * 8 + j;
  } else {
    int nt = (r >> 9) & 1;
    int kt = (r >> 10) & 15;
    int hb = (r >> 14) & 63;
    W = (mat == 1) ? Wx1 : Wh1;
    int gate = nt * 2 + (cl >> 3);
    gcol = gate * 512 + hb * 8 + (cl & 7);
    k = kt * 32 + qd * 8 + j;
    di = (size_t)mat * 1048576 + (size_t)hb * 16384 +
         ((size_t)(kt * 2 + nt) * 64 + ln) * 8 + j;
  }
  dst[di] = (f16)W[(size_t)k * 2048 + gcol];
}

// ---------------------------------------------------------------------------
// Epilogue: out[b][t] = bf + sum_{g<8} part8[g][b][t]
__global__ void reduce_out(const float* __restrict__ part8,
                           const float* __restrict__ bfp,
                           float* __restrict__ out) {
  int g = blockIdx.x * 256 + threadIdx.x;   // 262144 threads = b*1024+t
  float v = bfp[0];
#pragma unroll
  for (int j = 0; j < 8; ++j) v += part8[(size_t)j * (NB * NT_) + g];
  out[g] = v;
}

// ---------------------------------------------------------------------------
__global__ __launch_bounds__(512) void lstm_main(
    const float* __restrict__ xT,       // [T][B]
    const f16*  __restrict__ wsl,       // tiled weight slices (6 MB)
    const float* __restrict__ wx0,      // [2048]
    const float* __restrict__ bias0,    // [2048]
    const float* __restrict__ bias1,    // [2048]
    const float* __restrict__ wf,       // [512]
    unsigned short* p_hi, unsigned short* p_lo,   // [2][B][H] fp16 bits
    unsigned short* q_hi, unsigned short* q_lo,   // [2][B][H]
    unsigned int* arr,                  // 8 arrival counters, stride 32 uints
    unsigned int* flg,                  // 8 release flags,   stride 32 uints
    float* part8)                       // [8][B][T] output partials
{
  extern __shared__ char smem[];
  const int tid = threadIdx.x;
  const int wv  = tid >> 6;
  const int ln  = tid & 63;
  const int qd  = ln >> 4;
  const int cl  = ln & 15;
  const int bx  = blockIdx.x;
  const bool isL0 = (bx < 64);
  const float LO_SCALE = 1.0f / 1024.0f;

  // ---- stage this WG's weight slice(s) into LDS (once) ----
  int hb, rb;
  if (isL0) {
    hb = bx >> 1;
    rb = (bx & 1) * 128 + wv * 16;
    const int4* s0 = (const int4*)((const char*)wsl + (size_t)hb * 65536);
    int4* d = (int4*)smem;
    for (int i = tid; i < 4096; i += 512) d[i] = s0[i];
  } else {
    int ix = bx - 64;
    hb = ix >> 1;
    rb = (ix & 1) * 128 + wv * 16;
    const int4* s1 = (const int4*)((const char*)wsl + (1u << 21) + (size_t)hb * 32768);
    const int4* s2 = (const int4*)((const char*)wsl + (2u << 21) + (size_t)hb * 32768);
    int4* d = (int4*)smem;
    for (int i = tid; i < 2048; i += 512) { d[i] = s1[i]; d[2048 + i] = s2[i]; }
  }
  __syncthreads();

  // ---- loop-invariant per-lane constants ----
  float wx0v[4], b0c[4];
  float b1c0 = 0.f, b1c1 = 0.f, wfv = 0.f;
  if (isL0) {
#pragma unroll
    for (int nt = 0; nt < 4; ++nt) {
      int gc = nt * 512 + hb * 16 + cl;
      wx0v[nt] = wx0[gc];
      b0c[nt]  = bias0[gc];
    }
  } else {
    int u = cl & 7, g01 = cl >> 3;
    b1c0 = bias1[g01 * 512 + hb * 8 + u];
    b1c1 = bias1[(2 + g01) * 512 + hb * 8 + u];
    wfv  = wf[hb * 8 + u];
  }
  const int xccg = __builtin_amdgcn_s_getreg(XCC_GETREG_IMM) & 7;
  float cst[4] = {0.f, 0.f, 0.f, 0.f};

  for (int s = 0; s <= NT_; ++s) {
    if (isL0) {
      if (s < NT_) {
        const unsigned short* shi = p_hi + (size_t)((s + 1) & 1) * (NB * NH);
        const unsigned short* slo = p_lo + (size_t)((s + 1) & 1) * (NB * NH);
        const f16* ah = (const f16*)(shi + (size_t)(rb + cl) * NH) + qd * 8;
        const f16* al = (const f16*)(slo + (size_t)(rb + cl) * NH) + qd * 8;
        const f16x8* wlds = (const f16x8*)smem;
        // prefetch the whole step's A-fragments (128 VGPRs)
        u64 a0[16][2], a1[16][2];
#pragma unroll
        for (int kt = 0; kt < 16; ++kt) {
          a0[kt][0] = ld8(ah + kt * 32); a0[kt][1] = ld8(ah + kt * 32 + 4);
          a1[kt][0] = ld8(al + kt * 32); a1[kt][1] = ld8(al + kt * 32 + 4);
        }
        f32x4 acc[4]  = {{0,0,0,0},{0,0,0,0},{0,0,0,0},{0,0,0,0}};
        f32x4 accL[4] = {{0,0,0,0},{0,0,0,0},{0,0,0,0},{0,0,0,0}};
#pragma unroll
        for (int kt = 0; kt < 16; ++kt) {
          FragU ua, ub;
          ua.u[0] = a0[kt][0]; ua.u[1] = a0[kt][1];
          ub.u[0] = a1[kt][0]; ub.u[1] = a1[kt][1];
#pragma unroll
          for (int nt = 0; nt < 4; ++nt) {
            f16x8 bw = wlds[(kt * 4 + nt) * 64 + ln];
            acc[nt]  = __builtin_amdgcn_mfma_f32_16x16x32_f16(ua.v, bw, acc[nt], 0, 0, 0);
            accL[nt] = __builtin_amdgcn_mfma_f32_16x16x32_f16(ub.v, bw, accL[nt], 0, 0, 0);
          }
        }
        const int wpar = s & 1;
#pragma unroll
        for (int e = 0; e < 4; ++e) {
          int b = rb + qd * 4 + e;
          float xv = xT[s * NB + b];
          float gi = acc[0][e] + accL[0][e] * LO_SCALE + xv * wx0v[0] + b0c[0];
          float gf = acc[1][e] + accL[1][e] * LO_SCALE + xv * wx0v[1] + b0c[1];
          float gg = acc[2][e] + accL[2][e] * LO_SCALE + xv * wx0v[2] + b0c[2];
          float go = acc[3][e] + accL[3][e] * LO_SCALE + xv * wx0v[3] + b0c[3];
          float ii = sigm(gi), ff = sigm(gf), tg = tanhx(gg), oo = sigm(go);
          cst[e] = ff * cst[e] + ii * tg;
          float h = oo * tanhx(cst[e]);
          f16 hh = (f16)h;
          f16 hl = (f16)((h - (float)hh) * 1024.0f);
          size_t off = (size_t)wpar * (NB * NH) + (size_t)b * NH + hb * 16 + cl;
          __hip_atomic_store(p_hi + off, __builtin_bit_cast(unsigned short, hh),
                             __ATOMIC_RELAXED, __HIP_MEMORY_SCOPE_AGENT);
          __hip_atomic_store(p_lo + off, __builtin_bit_cast(unsigned short, hl),
                             __ATOMIC_RELAXED, __HIP_MEMORY_SCOPE_AGENT);
        }
      }
    } else {
      if (s >= 1) {
        const unsigned short* phi_ = p_hi + (size_t)((s + 1) & 1) * (NB * NH);
        const unsigned short* plo_ = p_lo + (size_t)((s + 1) & 1) * (NB * NH);
        const unsigned short* qhi_ = q_hi + (size_t)(s & 1) * (NB * NH);
        const unsigned short* qlo_ = q_lo + (size_t)(s & 1) * (NB * NH);
        const f16* aph = (const f16*)(phi_ + (size_t)(rb + cl) * NH) + qd * 8;
        const f16* apl = (const f16*)(plo_ + (size_t)(rb + cl) * NH) + qd * 8;
        const f16* aqh = (const f16*)(qhi_ + (size_t)(rb + cl) * NH) + qd * 8;
        const f16* aql = (const f16*)(qlo_ + (size_t)(rb + cl) * NH) + qd * 8;
        const f16x8* wx_ = (const f16x8*)smem;
        const f16x8* wh_ = (const f16x8*)(smem + 32768);
        f32x4 acc[2]  = {{0,0,0,0},{0,0,0,0}};
        f32x4 accL[2] = {{0,0,0,0},{0,0,0,0}};
        // ---- phase 1: q @ Wh1 (prefetch q streams fully) ----
        {
          u64 a0[16][2], a1[16][2];
#pragma unroll
          for (int kt = 0; kt < 16; ++kt) {
            a0[kt][0] = ld8(aqh + kt * 32); a0[kt][1] = ld8(aqh + kt * 32 + 4);
            a1[kt][0] = ld8(aql + kt * 32); a1[kt][1] = ld8(aql + kt * 32 + 4);
          }
#pragma unroll
          for (int kt = 0; kt < 16; ++kt) {
            FragU ua, ub;
            ua.u[0] = a0[kt][0]; ua.u[1] = a0[kt][1];
            ub.u[0] = a1[kt][0]; ub.u[1] = a1[kt][1];
#pragma unroll
            for (int nt = 0; nt < 2; ++nt) {
              f16x8 bhf = wh_[(kt * 2 + nt) * 64 + ln];
              acc[nt]  = __builtin_amdgcn_mfma_f32_16x16x32_f16(ua.v, bhf, acc[nt], 0, 0, 0);
              accL[nt] = __builtin_amdgcn_mfma_f32_16x16x32_f16(ub.v, bhf, accL[nt], 0, 0, 0);
            }
          }
        }
        // ---- phase 2: p @ Wx1 ----
        {
          u64 a0[16][2], a1[16][2];
#pragma unroll
          for (int kt = 0; kt < 16; ++kt) {
            a0[kt][0] = ld8(aph + kt * 32); a0[kt][1] = ld8(aph + kt * 32 + 4);
            a1[kt][0] = ld8(apl + kt * 32); a1[kt][1] = ld8(apl + kt * 32 + 4);
          }
#pragma unroll
          for (int kt = 0; kt < 16; ++kt) {
            FragU ua, ub;
            ua.u[0] = a0[kt][0]; ua.u[1] = a0[kt][1];
            ub.u[0] = a1[kt][0]; ub.u[1] = a1[kt][1];
#pragma unroll
            for (int nt = 0; nt < 2; ++nt) {
              f16x8 bxf = wx_[(kt * 2 + nt) * 64 + ln];
              acc[nt]  = __builtin_amdgcn_mfma_f32_16x16x32_f16(ua.v, bxf, acc[nt], 0, 0, 0);
              accL[nt] = __builtin_amdgcn_mfma_f32_16x16x32_f16(ub.v, bxf, accL[nt], 0, 0, 0);
            }
          }
        }
        const int wpar = (s - 1) & 1;
        const int tOut = s - 1;
        const bool hiHalf = (cl < 8);
        const int u = cl & 7;
#pragma unroll
        for (int e = 0; e < 4; ++e) {
          int b = rb + qd * 4 + e;
          float v0 = acc[0][e] + accL[0][e] * LO_SCALE + b1c0;
          float v1 = acc[1][e] + accL[1][e] * LO_SCALE + b1c1;
          float w0 = __shfl_xor(v0, 8, 16);
          float w1 = __shfl_xor(v1, 8, 16);
          float gi = hiHalf ? v0 : w0;
          float gf = hiHalf ? w0 : v0;
          float gg = hiHalf ? v1 : w1;
          float go = hiHalf ? w1 : v1;
          float ii = sigm(gi), ff = sigm(gf), tg = tanhx(gg), oo = sigm(go);
          cst[e] = ff * cst[e] + ii * tg;
          float h = oo * tanhx(cst[e]);
          size_t off = (size_t)wpar * (NB * NH) + (size_t)b * NH + hb * 8 + u;
          f16 hh = (f16)h;
          if (hiHalf) {
            __hip_atomic_store(q_hi + off, __builtin_bit_cast(unsigned short, hh),
                               __ATOMIC_RELAXED, __HIP_MEMORY_SCOPE_AGENT);
          } else {
            f16 hl = (f16)((h - (float)hh) * 1024.0f);
            __hip_atomic_store(q_lo + off, __builtin_bit_cast(unsigned short, hl),
                               __ATOMIC_RELAXED, __HIP_MEMORY_SCOPE_AGENT);
          }
          float po = hiHalf ? (wfv * h) : 0.0f;
#pragma unroll
          for (int m = 1; m < 16; m <<= 1) po += __shfl_xor(po, m, 16);
          if (cl == 0)
            atomicAdd(part8 + (size_t)(hb & 7) * (NB * NT_) + (size_t)b * NT_ + tOut, po);
        }
      }
    }

    if (s == NT_) break;   // no barrier needed after the last step

    // ---- hierarchical grid barrier ----
    __syncthreads();   // compiler drains vmcnt here: our agent stores are at LLC
    if (tid == 0) {
      __hip_atomic_fetch_add(arr + xccg * 32, 1u,
                             __ATOMIC_RELEASE, __HIP_MEMORY_SCOPE_AGENT);
      const unsigned tgt = (unsigned)NGRID * (unsigned)(s + 1);
      if (bx == 0) {   // master: wait for all arrivals, then broadcast release
        for (;;) {
          unsigned tot = 0;
#pragma unroll
          for (int j = 0; j < 8; ++j)
            tot += __hip_atomic_load(arr + j * 32, __ATOMIC_RELAXED,
                                     __HIP_MEMORY_SCOPE_AGENT);
          if (tot >= tgt) break;
          __builtin_amdgcn_s_sleep(1);
        }
#pragma unroll
        for (int j = 0; j < 8; ++j)
          __hip_atomic_store(flg + j * 32, (unsigned)(s + 1),
                             __ATOMIC_RELAXED, __HIP_MEMORY_SCOPE_AGENT);
      }
      while (__hip_atomic_load(flg + xccg * 32, __ATOMIC_RELAXED,
                               __HIP_MEMORY_SCOPE_AGENT) < (unsigned)(s + 1))
        __builtin_amdgcn_s_sleep(1);
    }
    __syncthreads();
    // NO cache-invalidate fence: h loads are sc0/sc1 (LLC-direct) by scope.
  }
}

// ---------------------------------------------------------------------------
extern "C" void kernel_launch(void* const* d_in, const int* in_sizes, int n_in,
                              void* d_out, int out_size, void* d_ws, size_t ws_size,
                              hipStream_t stream) {
  (void)in_sizes; (void)n_in; (void)out_size; (void)ws_size;
  const float* inp = (const float*)d_in[0];
  const float* Wx0 = (const float*)d_in[1];
  const float* Wh0 = (const float*)d_in[2];
  const float* b0  = (const float*)d_in[3];
  const float* Wx1 = (const float*)d_in[4];
  const float* Wh1 = (const float*)d_in[5];
  const float* b1  = (const float*)d_in[6];
  const float* Wf  = (const float*)d_in[7];
  const float* bf  = (const float*)d_in[8];

  const size_t kBH     = (size_t)NB * NH;               // 131072 elems
  const size_t OFF_W   = 0;                             // 6 MiB tiled fp16 W
  const size_t OFF_XT  = 6u << 20;                      // 1 MiB xT
  const size_t OFF_PHI = OFF_XT + (size_t)NT_ * NB * 4;
  const size_t OFF_PLO = OFF_PHI + 2 * kBH * 2;
  const size_t OFF_QHI = OFF_PLO + 2 * kBH * 2;
  const size_t OFF_QLO = OFF_QHI + 2 * kBH * 2;
  const size_t OFF_PART = OFF_QLO + 2 * kBH * 2;        // 8 MiB partials
  const size_t OFF_SYNC = OFF_PART + ((size_t)8 << 20); // 2 KiB barrier state

  char* ws = (char*)d_ws;
  f16* wsl = (f16*)(ws + OFF_W);
  float* xT = (float*)(ws + OFF_XT);
  unsigned short* phi = (unsigned short*)(ws + OFF_PHI);
  unsigned short* plo = (unsigned short*)(ws + OFF_PLO);
  unsigned short* qhi = (unsigned short*)(ws + OFF_QHI);
  unsigned short* qlo = (unsigned short*)(ws + OFF_QLO);
  float* part8 = (float*)(ws + OFF_PART);
  unsigned int* arr = (unsigned int*)(ws + OFF_SYNC);
  unsigned int* flg = (unsigned int*)(ws + OFF_SYNC + 1024);
  float* out = (float*)d_out;

  // zero h buffers + partials + barrier state (contiguous range)
  hipMemsetAsync(ws + OFF_PHI, 0, (OFF_SYNC + 2048) - OFF_PHI, stream);

  prep_xT<<<1024, 256, 0, stream>>>(inp, xT);
  prep_w<<<12288, 256, 0, stream>>>(Wh0, Wx1, Wh1, wsl);

  lstm_main<<<NGRID, 512, 65536, stream>>>(xT, wsl, Wx0, b0, b1, Wf,
                                           phi, plo, qhi, qlo, arr, flg, part8);

  reduce_out<<<1024, 256, 0, stream>>>(part8, bf, out);
}

// Round 3
// 19798.071 us; speedup vs baseline: 1.6981x; 1.6981x over previous
//
#include <hip/hip_runtime.h>

// ============================================================================
// 2-layer LSTM (B=256, T=1024, H=512, in=1) + linear head. fp32 in/out.
//
// R3: dataflow-pipelined persistent kernel, 192 WGs x 512 thr.
//  Partition: batch 4 chunks x 64 rows.
//   L0: 16 slices (128 gate-cols, 128KB LDS) x 4 chunks = 64 WGs
//   L1: 32 slices ( 64 gate-cols, Wx1+Wh1 = 128KB LDS) x 4 chunks = 128 WGs
//  h transport (the R1/R2 killer was per-step LLC latency chains):
//   - monotonic RING=16 slot per step; producers write-through with relaxed
//     agent-scope 8B stores (coalesced 16B/lane pairs) -> LLC always fresh
//   - consumers use PLAIN CACHED dwordx4 loads: addresses unseen for 16 steps
//     + a buffer_inv sc1 every 16 steps per WG => L2 can never serve stale;
//     loads are pipelined line-dense L2/LLC-throughput, not latency-bound.
//   - per-chunk progress counters (ctr_p/ctr_q at LLC) replace the global
//     barrier; chunks are fully independent pipelines; L0 runs ahead up to
//     RING-1 steps (ring guard), L1 chases.
// Weights LDS-resident fp16 (MFMA B-frag order), 128KB/WG via
// hipFuncSetAttribute(MaxDynamicSharedMemorySize). h = fp16 hi + (lo*1024).
// MFMA f32_16x16x32_f16, fp32 cell state in regs (verified R1/R2: 6.1e-5).
// ============================================================================

typedef _Float16 f16;
typedef _Float16 f16x8 __attribute__((ext_vector_type(8)));
typedef float f32x4 __attribute__((ext_vector_type(4)));
typedef unsigned long long u64;

#define NB 256
#define NT_ 1024
#define NH 512
#define RING 16
#define SLOT (NB * NH)      // elems per ring slot

__device__ __forceinline__ float sigm(float x)  { return 1.0f / (1.0f + __expf(-x)); }
__device__ __forceinline__ float tanhx(float x) { return 2.0f / (1.0f + __expf(-2.0f * x)) - 1.0f; }

// write-through 8B store to LLC (agent scope, relaxed)
__device__ __forceinline__ void st8(unsigned short* p, u64 v) {
  __hip_atomic_store((u64*)p, v, __ATOMIC_RELAXED, __HIP_MEMORY_SCOPE_AGENT);
}
__device__ __forceinline__ unsigned ldc(const unsigned* p) {
  return __hip_atomic_load(p, __ATOMIC_RELAXED, __HIP_MEMORY_SCOPE_AGENT);
}

// ---------------------------------------------------------------------------
__global__ void prep_xT(const float* __restrict__ inp, float* __restrict__ xT) {
  int g = blockIdx.x * 256 + threadIdx.x;
  int t = g >> 8, b = g & 255;
  xT[t * NB + b] = inp[b * NT_ + t];
}

// ---------------------------------------------------------------------------
// fp32 -> fp16 weights in MFMA B-fragment order.
// L0 (Wh0): 16 slices x [nh<2][gate<4][kt<16][lane<64][j<8]; slice=65536 elems.
//   gcol = gate*512 + sl*32 + nh*16 + cl
// L1 (Wx1, Wh1): 32 slices x [nh<2][jt<2][kt<16][lane<64][j<8]; slice=32768.
//   gate = jt*2 + (cl>>3); gcol = gate*512 + sl*16 + nh*8 + (cl&7)
__global__ void prep_w(const float* __restrict__ Wh0,
                       const float* __restrict__ Wx1,
                       const float* __restrict__ Wh1,
                       f16* __restrict__ dst) {
  int g = blockIdx.x * 256 + threadIdx.x;   // 3 * 2^20 threads
  int mat = g >> 20;
  int r = g & 0xFFFFF;
  int j = r & 7, ln = (r >> 3) & 63, kt = (r >> 9) & 15;
  int cl = ln & 15, qd = ln >> 4;
  int k = kt * 32 + qd * 8 + j;
  size_t di; int gcol; const float* W;
  if (mat == 0) {
    int gt = (r >> 13) & 3, nh = (r >> 15) & 1, sl = (r >> 16) & 15;
    W = Wh0;
    gcol = gt * 512 + sl * 32 + nh * 16 + cl;
    di = (size_t)sl * 65536 + (((size_t)(nh * 4 + gt) * 16 + kt) * 64 + ln) * 8 + j;
  } else {
    int jt = (r >> 13) & 1, nh = (r >> 14) & 1, sl = (r >> 15) & 31;
    W = (mat == 1) ? Wx1 : Wh1;
    int gate = jt * 2 + (cl >> 3);
    gcol = gate * 512 + sl * 16 + nh * 8 + (cl & 7);
    di = (size_t)mat * 1048576 + (size_t)sl * 32768 +
         (((size_t)(nh * 2 + jt) * 16 + kt) * 64 + ln) * 8 + j;
  }
  dst[di] = (f16)W[(size_t)k * 2048 + gcol];
}

// ---------------------------------------------------------------------------
__global__ void reduce_out(const float* __restrict__ part8,
                           const float* __restrict__ bfp,
                           float* __restrict__ out) {
  int g = blockIdx.x * 256 + threadIdx.x;   // 262144 = b*1024+t
  float v = bfp[0];
#pragma unroll
  for (int j = 0; j < 8; ++j) v += part8[(size_t)j * (NB * NT_) + g];
  out[g] = v;
}

// ---------------------------------------------------------------------------
__global__ __launch_bounds__(512) void lstm_main(
    const float* __restrict__ xT,       // [T][B]
    const f16*  __restrict__ wsl,       // tiled fp16 weights (6 MB)
    const float* __restrict__ wx0,      // [2048]
    const float* __restrict__ bias0,    // [2048]
    const float* __restrict__ bias1,    // [2048]
    const float* __restrict__ wf,       // [512]
    unsigned short* p_hi, unsigned short* p_lo,   // [RING][B][H]
    unsigned short* q_hi, unsigned short* q_lo,   // [RING][B][H]
    unsigned int* ctr,                  // ctr_p[c]=ctr[c*32]; ctr_q[c]=ctr[128+c*32]
    float* part8)                       // [8][B][T]
{
  extern __shared__ char smem[];
  const int tid = threadIdx.x;
  const int wv = tid >> 6, ln = tid & 63;
  const int qd = ln >> 4, cl = ln & 15;
  const int rt = wv >> 1, nh = wv & 1;
  const int bx = blockIdx.x;
  const bool isL0 = (bx < 64);
  const float LO = 1.0f / 1024.0f;

  int c, sl;
  if (isL0) { c = bx >> 4; sl = bx & 15; }
  else      { int ix = bx - 64; c = ix >> 5; sl = ix & 31; }
  const int rbase = c * 64 + rt * 16;

  // ---- stage weight slice(s) into LDS ----
  if (isL0) {
    const int4* s0 = (const int4*)wsl + (size_t)sl * 8192;   // 128 KB
    int4* d = (int4*)smem;
    for (int i = tid; i < 8192; i += 512) d[i] = s0[i];
  } else {
    const int4* s1 = (const int4*)wsl + 131072 + (size_t)sl * 4096;  // Wx1 64 KB
    const int4* s2 = (const int4*)wsl + 262144 + (size_t)sl * 4096;  // Wh1 64 KB
    int4* d = (int4*)smem;
    for (int i = tid; i < 4096; i += 512) { d[i] = s1[i]; d[4096 + i] = s2[i]; }
  }
  __syncthreads();

  // ---- loop-invariant constants ----
  float wx0v[4], b0c[4];
  float b1c0 = 0.f, b1c1 = 0.f, wfv = 0.f;
  if (isL0) {
#pragma unroll
    for (int g = 0; g < 4; ++g) {
      int gc = g * 512 + sl * 32 + nh * 16 + cl;
      wx0v[g] = wx0[gc];
      b0c[g] = bias0[gc];
    }
  } else {
    int u = cl & 7, g01 = cl >> 3;
    int base = sl * 16 + nh * 8 + u;
    b1c0 = bias1[g01 * 512 + base];
    b1c1 = bias1[(2 + g01) * 512 + base];
    wfv = wf[base];
  }
  f16* stg_hi = (f16*)(smem + 131072);
  f16* stg_lo = (f16*)(smem + 131072 + (isL0 ? 4096 : 2048));
  unsigned* cp = ctr + c * 32;
  unsigned* cq = ctr + 128 + c * 32;
  float cst[4] = {0.f, 0.f, 0.f, 0.f};

  for (int s = 0; s < NT_; ++s) {
    // ---- 1: wait on per-chunk dataflow counters (leader polls LLC) ----
    if (tid == 0) {
      if (isL0) {
        unsigned t1 = 16u * (unsigned)s;                  // p_{s-1} complete
        while (ldc(cp) < t1) __builtin_amdgcn_s_sleep(2);
        if (s >= RING) {                                  // ring guard: L1 done s-16
          unsigned t2 = 32u * (unsigned)(s - RING + 1);
          while (ldc(cq) < t2) __builtin_amdgcn_s_sleep(2);
        }
      } else {
        unsigned t1 = 16u * (unsigned)(s + 1);            // p_s ready
        while (ldc(cp) < t1) __builtin_amdgcn_s_sleep(2);
        if (s) {
          unsigned t2 = 32u * (unsigned)s;                // q_{s-1} ready
          while (ldc(cq) < t2) __builtin_amdgcn_s_sleep(2);
        }
      }
    }
    __syncthreads();

    // ---- 2: periodic L1/L2 invalidate (between ring-slot reuses) ----
    if ((s & (RING - 1)) == 0 && s) {
      if (wv == 0)
        asm volatile("buffer_inv sc1\n\ts_waitcnt vmcnt(0)" ::: "memory");
      __syncthreads();
    }

    const int slot_r = (s + RING - 1) & (RING - 1);   // h_{s-1}
    const int slot_w = s & (RING - 1);                // h_s

    if (isL0) {
      // ======== layer 0: p_s = LSTM(x_s, p_{s-1}) ========
      const f16* ah = (const f16*)p_hi + (size_t)slot_r * SLOT + (size_t)(rbase + cl) * NH + qd * 8;
      const f16* al = (const f16*)p_lo + (size_t)slot_r * SLOT + (size_t)(rbase + cl) * NH + qd * 8;
      const f16x8* wlds = (const f16x8*)smem;
      f32x4 acc[4]  = {{0,0,0,0},{0,0,0,0},{0,0,0,0},{0,0,0,0}};
      f32x4 accL[4] = {{0,0,0,0},{0,0,0,0},{0,0,0,0},{0,0,0,0}};
#pragma unroll
      for (int kt = 0; kt < 16; ++kt) {
        f16x8 a0 = *(const f16x8*)(ah + kt * 32);
        f16x8 a1 = *(const f16x8*)(al + kt * 32);
#pragma unroll
        for (int g = 0; g < 4; ++g) {
          f16x8 bw = wlds[((nh * 4 + g) * 16 + kt) * 64 + ln];
          acc[g]  = __builtin_amdgcn_mfma_f32_16x16x32_f16(a0, bw, acc[g], 0, 0, 0);
          accL[g] = __builtin_amdgcn_mfma_f32_16x16x32_f16(a1, bw, accL[g], 0, 0, 0);
        }
      }
#pragma unroll
      for (int e = 0; e < 4; ++e) {
        int r = rt * 16 + qd * 4 + e;
        int b = c * 64 + r;
        float xv = xT[s * NB + b];
        float gi = acc[0][e] + accL[0][e] * LO + xv * wx0v[0] + b0c[0];
        float gf = acc[1][e] + accL[1][e] * LO + xv * wx0v[1] + b0c[1];
        float gg = acc[2][e] + accL[2][e] * LO + xv * wx0v[2] + b0c[2];
        float go = acc[3][e] + accL[3][e] * LO + xv * wx0v[3] + b0c[3];
        float ii = sigm(gi), ff = sigm(gf), tg = tanhx(gg), oo = sigm(go);
        cst[e] = ff * cst[e] + ii * tg;
        float h = oo * tanhx(cst[e]);
        f16 hh = (f16)h;
        f16 hl = (f16)((h - (float)hh) * 1024.0f);
        stg_hi[r * 32 + nh * 16 + cl] = hh;
        stg_lo[r * 32 + nh * 16 + cl] = hl;
      }
      __syncthreads();
      // coop write-through store: 64 rows x 32 units, 16B/thread
      {
        int t = tid & 255, r = t >> 2, part = t & 3;
        f16* src = (tid < 256 ? stg_hi : stg_lo) + r * 32 + part * 8;
        unsigned short* dg = (tid < 256 ? p_hi : p_lo) +
            (size_t)slot_w * SLOT + (size_t)(c * 64 + r) * NH + sl * 32 + part * 8;
        u64 v0 = *(const u64*)src, v1 = *((const u64*)src + 1);
        st8(dg, v0); st8(dg + 4, v1);
      }
    } else {
      // ======== layer 1: q_s = LSTM(p_s, q_{s-1}) ========
      const f16* aph = (const f16*)p_hi + (size_t)slot_w * SLOT + (size_t)(rbase + cl) * NH + qd * 8;
      const f16* apl = (const f16*)p_lo + (size_t)slot_w * SLOT + (size_t)(rbase + cl) * NH + qd * 8;
      const f16* aqh = (const f16*)q_hi + (size_t)slot_r * SLOT + (size_t)(rbase + cl) * NH + qd * 8;
      const f16* aql = (const f16*)q_lo + (size_t)slot_r * SLOT + (size_t)(rbase + cl) * NH + qd * 8;
      const f16x8* wx_ = (const f16x8*)smem;
      const f16x8* wh_ = (const f16x8*)(smem + 65536);
      f32x4 acc[2]  = {{0,0,0,0},{0,0,0,0}};
      f32x4 accL[2] = {{0,0,0,0},{0,0,0,0}};
#pragma unroll
      for (int kt = 0; kt < 16; ++kt) {
        f16x8 ph = *(const f16x8*)(aph + kt * 32);
        f16x8 pl = *(const f16x8*)(apl + kt * 32);
        f16x8 qh = *(const f16x8*)(aqh + kt * 32);
        f16x8 ql = *(const f16x8*)(aql + kt * 32);
#pragma unroll
        for (int jt = 0; jt < 2; ++jt) {
          f16x8 bxf = wx_[((nh * 2 + jt) * 16 + kt) * 64 + ln];
          f16x8 bhf = wh_[((nh * 2 + jt) * 16 + kt) * 64 + ln];
          acc[jt]  = __builtin_amdgcn_mfma_f32_16x16x32_f16(ph, bxf, acc[jt], 0, 0, 0);
          accL[jt] = __builtin_amdgcn_mfma_f32_16x16x32_f16(pl, bxf, accL[jt], 0, 0, 0);
          acc[jt]  = __builtin_amdgcn_mfma_f32_16x16x32_f16(qh, bhf, acc[jt], 0, 0, 0);
          accL[jt] = __builtin_amdgcn_mfma_f32_16x16x32_f16(ql, bhf, accL[jt], 0, 0, 0);
        }
      }
      const bool hiH = (cl < 8);
#pragma unroll
      for (int e = 0; e < 4; ++e) {
        int r = rt * 16 + qd * 4 + e;
        int b = c * 64 + r;
        float v0 = acc[0][e] + accL[0][e] * LO + b1c0;   // i / f
        float v1 = acc[1][e] + accL[1][e] * LO + b1c1;   // g / o
        float w0 = __shfl_xor(v0, 8, 16);
        float w1 = __shfl_xor(v1, 8, 16);
        float gi = hiH ? v0 : w0;
        float gf = hiH ? w0 : v0;
        float gg = hiH ? v1 : w1;
        float go = hiH ? w1 : v1;
        float ii = sigm(gi), ff = sigm(gf), tg = tanhx(gg), oo = sigm(go);
        cst[e] = ff * cst[e] + ii * tg;
        float h = oo * tanhx(cst[e]);
        int su = r * 16 + nh * 8 + (cl & 7);
        if (hiH) {
          stg_hi[su] = (f16)h;
        } else {
          f16 hh = (f16)h;
          stg_lo[su] = (f16)((h - (float)hh) * 1024.0f);
        }
        float po = hiH ? (wfv * h) : 0.0f;
#pragma unroll
        for (int m = 1; m < 16; m <<= 1) po += __shfl_xor(po, m, 16);
        if (cl == 0)
          atomicAdd(part8 + (size_t)(sl & 7) * (NB * NT_) + (size_t)b * NT_ + s, po);
      }
      __syncthreads();
      // coop write-through store: 64 rows x 16 units, 16B/thread (256 threads)
      if (tid < 256) {
        int t = tid & 127, r = t >> 1, part = t & 1;
        f16* src = (tid < 128 ? stg_hi : stg_lo) + r * 16 + part * 8;
        unsigned short* dg = (tid < 128 ? q_hi : q_lo) +
            (size_t)slot_w * SLOT + (size_t)(c * 64 + r) * NH + sl * 16 + part * 8;
        u64 v0 = *(const u64*)src, v1 = *((const u64*)src + 1);
        st8(dg, v0); st8(dg + 4, v1);
      }
    }

    __syncthreads();   // all threads' WT stores drained (vmcnt 0) before bump
    if (tid == 0)
      __hip_atomic_fetch_add(isL0 ? cp : cq, 1u,
                             __ATOMIC_RELAXED, __HIP_MEMORY_SCOPE_AGENT);
  }
}

// ---------------------------------------------------------------------------
extern "C" void kernel_launch(void* const* d_in, const int* in_sizes, int n_in,
                              void* d_out, int out_size, void* d_ws, size_t ws_size,
                              hipStream_t stream) {
  (void)in_sizes; (void)n_in; (void)out_size; (void)ws_size;
  const float* inp = (const float*)d_in[0];
  const float* Wx0 = (const float*)d_in[1];
  const float* Wh0 = (const float*)d_in[2];
  const float* b0  = (const float*)d_in[3];
  const float* Wx1 = (const float*)d_in[4];
  const float* Wh1 = (const float*)d_in[5];
  const float* b1  = (const float*)d_in[6];
  const float* Wf  = (const float*)d_in[7];
  const float* bf  = (const float*)d_in[8];

  const size_t MB = 1u << 20;
  const size_t OFF_W    = 0;                 // 6 MiB tiled fp16 weights
  const size_t OFF_XT   = 6 * MB;            // 1 MiB
  const size_t OFF_PHI  = 7 * MB;            // 4 MiB (RING x 256 KB)
  const size_t OFF_PLO  = 11 * MB;
  const size_t OFF_QHI  = 15 * MB;
  const size_t OFF_QLO  = 19 * MB;
  const size_t OFF_PART = 23 * MB;           // 8 MiB
  const size_t OFF_CTR  = 31 * MB;           // 1 KiB

  char* ws = (char*)d_ws;
  f16* wsl = (f16*)(ws + OFF_W);
  float* xT = (float*)(ws + OFF_XT);
  unsigned short* phi = (unsigned short*)(ws + OFF_PHI);
  unsigned short* plo = (unsigned short*)(ws + OFF_PLO);
  unsigned short* qhi = (unsigned short*)(ws + OFF_QHI);
  unsigned short* qlo = (unsigned short*)(ws + OFF_QLO);
  float* part8 = (float*)(ws + OFF_PART);
  unsigned int* ctr = (unsigned int*)(ws + OFF_CTR);
  float* out = (float*)d_out;

  // opt into 136 KB dynamic LDS (160 KB/CU on gfx950)
  hipFuncSetAttribute((const void*)lstm_main,
                      hipFuncAttributeMaxDynamicSharedMemorySize, 139264);

  // zero rings + partials + counters (24 MiB + 1 KiB, contiguous)
  hipMemsetAsync(ws + OFF_PHI, 0, (OFF_CTR + 1024) - OFF_PHI, stream);

  prep_xT<<<1024, 256, 0, stream>>>(inp, xT);
  prep_w<<<12288, 256, 0, stream>>>(Wh0, Wx1, Wh1, wsl);

  lstm_main<<<192, 512, 139264, stream>>>(xT, wsl, Wx0, b0, b1, Wf,
                                          phi, plo, qhi, qlo, ctr, part8);

  reduce_out<<<1024, 256, 0, stream>>>(part8, bf, out);
}

// Round 4
// 13225.075 us; speedup vs baseline: 2.5421x; 1.4970x over previous
//
#include <hip/hip_runtime.h>

// ============================================================================
// 2-layer LSTM (B=256, T=1024, H=512, in=1) + linear head. fp32 in/out.
//
// R4: dataflow pipeline, 256 blocks x 256 thr (64 early-exit), 1 WG/CU.
//  Batch: 4 chunks x 64 rows. L0: 16 slices/chunk, L1: 32 slices/chunk.
//  XCD-affinity: chunk c -> L0 on bx%8==2c, L1 on bx%8==2c+1 (round-robin
//  dispatch heuristic; perf-only, correctness placement-independent).
//  vs R3:
//   - 4 waves/WG, each wave computes BOTH nh unit-groups -> A-fragment loads
//     halve (no nh duplication): L0 128 KB, L1 256 KB issued per WG per step.
//   - per-slice flag words (not shared atomic counters): producer stores s+1
//     after vmcnt-drained WT stores; consumers poll 16/32 flags lane-parallel
//     (one line read + ballot) per-wave, no leader/syncthreads round trip.
//     asm "" memory fence after poll pins plain-load ordering.
//   - L1 runs q@Wh1 phase (loads+MFMA) BEFORE polling for p_s -> q work hides
//     inside the L0 dependency wait.
//  h transport: RING=16 slots; WT agent stores to LLC; plain cached loads +
//  buffer_inv sc1 once per ring epoch (addresses touched once per epoch =>
//  never stale). Verified pattern from R3 (absmax 6.1e-5).
// ============================================================================

typedef _Float16 f16;
typedef _Float16 f16x8 __attribute__((ext_vector_type(8)));
typedef float f32x4 __attribute__((ext_vector_type(4)));
typedef unsigned long long u64;

#define NB 256
#define NT_ 1024
#define NH 512
#define RING 16
#define SLOT (NB * NH)

__device__ __forceinline__ float sigm(float x)  { return 1.0f / (1.0f + __expf(-x)); }
__device__ __forceinline__ float tanhx(float x) { return 2.0f / (1.0f + __expf(-2.0f * x)) - 1.0f; }

__device__ __forceinline__ void st8(unsigned short* p, u64 v) {
  __hip_atomic_store((u64*)p, v, __ATOMIC_RELAXED, __HIP_MEMORY_SCOPE_AGENT);
}
__device__ __forceinline__ unsigned ldf(const unsigned* p) {
  return __hip_atomic_load(p, __ATOMIC_RELAXED, __HIP_MEMORY_SCOPE_AGENT);
}
// Poll nf flags (nf = 16 or 32, power of 2) until all >= thr. Lane-parallel:
// lane ln reads flag ln%nf (one LLC line), ballot across the wave. The empty
// asm with memory clobber stops the compiler hoisting subsequent plain loads
// above the loop (HW issues VMEM in order per wave, so this suffices).
__device__ __forceinline__ void pollf(const unsigned* base, int nf, unsigned thr, int ln) {
  const unsigned* a = base + (ln & (nf - 1));
  for (;;) {
    unsigned v = ldf(a);
    if (!~__ballot(v >= thr)) break;
    __builtin_amdgcn_s_sleep(2);
  }
  asm volatile("" ::: "memory");
}

// ---------------------------------------------------------------------------
__global__ void prep_xT(const float* __restrict__ inp, float* __restrict__ xT) {
  int g = blockIdx.x * 256 + threadIdx.x;
  int t = g >> 8, b = g & 255;
  xT[t * NB + b] = inp[b * NT_ + t];
}

// ---------------------------------------------------------------------------
// fp32 -> fp16 weights in MFMA B-fragment order (verified R3).
// L0 (Wh0): 16 slices x [nh<2][gate<4][kt<16][lane<64][j<8]; slice=65536 elems.
// L1 (Wx1, Wh1): 32 slices x [nh<2][jt<2][kt<16][lane<64][j<8]; slice=32768.
__global__ void prep_w(const float* __restrict__ Wh0,
                       const float* __restrict__ Wx1,
                       const float* __restrict__ Wh1,
                       f16* __restrict__ dst) {
  int g = blockIdx.x * 256 + threadIdx.x;   // 3 * 2^20 threads
  int mat = g >> 20;
  int r = g & 0xFFFFF;
  int j = r & 7, ln = (r >> 3) & 63, kt = (r >> 9) & 15;
  int cl = ln & 15, qd = ln >> 4;
  int k = kt * 32 + qd * 8 + j;
  size_t di; int gcol; const float* W;
  if (mat == 0) {
    int gt = (r >> 13) & 3, nh = (r >> 15) & 1, sl = (r >> 16) & 15;
    W = Wh0;
    gcol = gt * 512 + sl * 32 + nh * 16 + cl;
    di = (size_t)sl * 65536 + (((size_t)(nh * 4 + gt) * 16 + kt) * 64 + ln) * 8 + j;
  } else {
    int jt = (r >> 13) & 1, nh = (r >> 14) & 1, sl = (r >> 15) & 31;
    W = (mat == 1) ? Wx1 : Wh1;
    int gate = jt * 2 + (cl >> 3);
    gcol = gate * 512 + sl * 16 + nh * 8 + (cl & 7);
    di = (size_t)mat * 1048576 + (size_t)sl * 32768 +
         (((size_t)(nh * 2 + jt) * 16 + kt) * 64 + ln) * 8 + j;
  }
  dst[di] = (f16)W[(size_t)k * 2048 + gcol];
}

// ---------------------------------------------------------------------------
__global__ void reduce_out(const float* __restrict__ part8,
                           const float* __restrict__ bfp,
                           float* __restrict__ out) {
  int g = blockIdx.x * 256 + threadIdx.x;   // 262144 = b*1024+t
  float v = bfp[0];
#pragma unroll
  for (int j = 0; j < 8; ++j) v += part8[(size_t)j * (NB * NT_) + g];
  out[g] = v;
}

// ---------------------------------------------------------------------------
__global__ __launch_bounds__(256) void lstm_main(
    const float* __restrict__ xT,       // [T][B]
    const f16*  __restrict__ wsl,       // tiled fp16 weights (6 MB)
    const float* __restrict__ wx0,      // [2048]
    const float* __restrict__ bias0,    // [2048]
    const float* __restrict__ bias1,    // [2048]
    const float* __restrict__ wf,       // [512]
    unsigned short* p_hi, unsigned short* p_lo,   // [RING][B][H]
    unsigned short* q_hi, unsigned short* q_lo,   // [RING][B][H]
    unsigned int* pf,                   // [4][32] L0 slice flags (16 used/chunk)
    unsigned int* qf,                   // [4][32] L1 slice flags
    float* part8)                       // [8][B][T]
{
  extern __shared__ char smem[];
  const int tid = threadIdx.x;
  const int wv = tid >> 6, ln = tid & 63;
  const int qd = ln >> 4, cl = ln & 15;
  const int bx = blockIdx.x;
  const int r8 = bx & 7, idx = bx >> 3;
  const bool isL0 = !(r8 & 1);
  const int c = r8 >> 1;
  const int sl = idx;
  if (isL0 && idx >= 16) return;        // 64 spare WGs exit
  const float LO = 1.0f / 1024.0f;
  const int rb = c * 64 + wv * 16;      // this wave's batch-row base

  // ---- stage weight slice(s) into LDS (once) ----
  if (isL0) {
    const int4* s0 = (const int4*)wsl + (size_t)sl * 8192;           // 128 KB
    int4* d = (int4*)smem;
    for (int i = tid; i < 8192; i += 256) d[i] = s0[i];
  } else {
    const int4* s1 = (const int4*)wsl + 131072 + (size_t)sl * 4096;  // Wx1 64 KB
    const int4* s2 = (const int4*)wsl + 262144 + (size_t)sl * 4096;  // Wh1 64 KB
    int4* d = (int4*)smem;
    for (int i = tid; i < 4096; i += 256) { d[i] = s1[i]; d[4096 + i] = s2[i]; }
  }
  __syncthreads();

  // ---- loop-invariant constants (both nh groups per lane now) ----
  float wx0v[2][4], b0c[2][4];
  float b1c0[2], b1c1[2], wfv[2];
  if (isL0) {
#pragma unroll
    for (int nh = 0; nh < 2; ++nh)
#pragma unroll
      for (int g = 0; g < 4; ++g) {
        int gc = g * 512 + sl * 32 + nh * 16 + cl;
        wx0v[nh][g] = wx0[gc];
        b0c[nh][g] = bias0[gc];
      }
  } else {
    int u = cl & 7, g01 = cl >> 3;
#pragma unroll
    for (int nh = 0; nh < 2; ++nh) {
      int base = sl * 16 + nh * 8 + u;
      b1c0[nh] = bias1[g01 * 512 + base];
      b1c1[nh] = bias1[(2 + g01) * 512 + base];
      wfv[nh] = wf[base];
    }
  }
  unsigned* pfc = pf + c * 32;
  unsigned* qfc = qf + c * 32;
  float cst[2][4] = {{0.f,0.f,0.f,0.f},{0.f,0.f,0.f,0.f}};

  for (int s = 0; s < NT_; ++s) {
    // ---- ring-epoch L1/L2 invalidate (addresses reused every 16 steps) ----
    if ((s & (RING - 1)) == 0 && s) {
      __syncthreads();
      if (wv == 0)
        asm volatile("buffer_inv sc1\n\ts_waitcnt vmcnt(0)" ::: "memory");
      __syncthreads();
    }
    const int slot_r = (s + RING - 1) & (RING - 1);   // h_{s-1}
    const int slot_w = s & (RING - 1);                // h_s

    if (isL0) {
      // ======== layer 0: p_s = LSTM(x_s, p_{s-1}) ========
      if (s) pollf(pfc, 16, (unsigned)s, ln);          // all slices done s-1
      // x prefetch (early issue; used in epilogue)
      float xv[4];
#pragma unroll
      for (int e = 0; e < 4; ++e) xv[e] = xT[s * NB + rb + qd * 4 + e];
      const f16* ah = (const f16*)p_hi + (size_t)slot_r * SLOT + (size_t)(rb + cl) * NH + qd * 8;
      const f16* al = (const f16*)p_lo + (size_t)slot_r * SLOT + (size_t)(rb + cl) * NH + qd * 8;
      const f16x8* wl = (const f16x8*)smem;
      f32x4 acc[8]  = {};
      f32x4 accL[8] = {};
#pragma unroll
      for (int kt = 0; kt < 16; ++kt) {
        f16x8 a0 = *(const f16x8*)(ah + kt * 32);
        f16x8 a1 = *(const f16x8*)(al + kt * 32);
#pragma unroll
        for (int t8 = 0; t8 < 8; ++t8) {   // t8 = nh*4 + gate
          f16x8 bw = wl[(t8 * 16 + kt) * 64 + ln];
          acc[t8]  = __builtin_amdgcn_mfma_f32_16x16x32_f16(a0, bw, acc[t8], 0, 0, 0);
          accL[t8] = __builtin_amdgcn_mfma_f32_16x16x32_f16(a1, bw, accL[t8], 0, 0, 0);
        }
      }
      f16* sh  = (f16*)(smem + 131072);      // 64 x 32 hi (4 KB)
      f16* slo = sh + 2048;                  // 64 x 32 lo (4 KB)
#pragma unroll
      for (int nh = 0; nh < 2; ++nh)
#pragma unroll
        for (int e = 0; e < 4; ++e) {
          int r = wv * 16 + qd * 4 + e;
          float gi = acc[nh*4+0][e] + accL[nh*4+0][e] * LO + xv[e] * wx0v[nh][0] + b0c[nh][0];
          float gf = acc[nh*4+1][e] + accL[nh*4+1][e] * LO + xv[e] * wx0v[nh][1] + b0c[nh][1];
          float gg = acc[nh*4+2][e] + accL[nh*4+2][e] * LO + xv[e] * wx0v[nh][2] + b0c[nh][2];
          float go = acc[nh*4+3][e] + accL[nh*4+3][e] * LO + xv[e] * wx0v[nh][3] + b0c[nh][3];
          float ii = sigm(gi), ff = sigm(gf), tg = tanhx(gg), oo = sigm(go);
          cst[nh][e] = ff * cst[nh][e] + ii * tg;
          float h = oo * tanhx(cst[nh][e]);
          f16 hh = (f16)h;
          sh[r * 32 + nh * 16 + cl]  = hh;
          slo[r * 32 + nh * 16 + cl] = (f16)((h - (float)hh) * 1024.0f);
        }
      __syncthreads();
      // ring-overwrite guard: L1 must have finished step s-16
      if (s >= RING) pollf(qfc, 32, (unsigned)(s - RING + 1), ln);
      // coop WT store: 64 rows x 32 units x {hi,lo}, 8B pieces
      {
        unsigned short* bh = p_hi + (size_t)slot_w * SLOT;
        unsigned short* bl = p_lo + (size_t)slot_w * SLOT;
        for (int i = tid; i < 1024; i += 256) {
          int strm = i >> 9, id2 = i & 511, r = id2 >> 3, j = id2 & 7;
          const f16* src = (strm ? slo : sh) + r * 32 + j * 4;
          unsigned short* dst = (strm ? bl : bh) + (size_t)(c * 64 + r) * NH + sl * 32 + j * 4;
          st8(dst, *(const u64*)src);
        }
      }
      __syncthreads();   // all waves' stores vmcnt-drained at LLC
      if (tid == 0)
        __hip_atomic_store(pfc + sl, (unsigned)(s + 1),
                           __ATOMIC_RELAXED, __HIP_MEMORY_SCOPE_AGENT);
    } else {
      // ======== layer 1: q_s = LSTM(p_s, q_{s-1}) ========
      // phase 1: q_{s-1} @ Wh1 — hides inside the wait for L0's p_s flag
      if (s) pollf(qfc, 32, (unsigned)s, ln);
      const f16* aqh = (const f16*)q_hi + (size_t)slot_r * SLOT + (size_t)(rb + cl) * NH + qd * 8;
      const f16* aql = (const f16*)q_lo + (size_t)slot_r * SLOT + (size_t)(rb + cl) * NH + qd * 8;
      const f16x8* wx_ = (const f16x8*)smem;
      const f16x8* wh_ = (const f16x8*)(smem + 65536);
      f32x4 acc[4]  = {};
      f32x4 accL[4] = {};
#pragma unroll
      for (int kt = 0; kt < 16; ++kt) {
        f16x8 a0 = *(const f16x8*)(aqh + kt * 32);
        f16x8 a1 = *(const f16x8*)(aql + kt * 32);
#pragma unroll
        for (int t4 = 0; t4 < 4; ++t4) {   // t4 = nh*2 + jt
          f16x8 bw = wh_[(t4 * 16 + kt) * 64 + ln];
          acc[t4]  = __builtin_amdgcn_mfma_f32_16x16x32_f16(a0, bw, acc[t4], 0, 0, 0);
          accL[t4] = __builtin_amdgcn_mfma_f32_16x16x32_f16(a1, bw, accL[t4], 0, 0, 0);
        }
      }
      // phase 2: p_s @ Wx1
      pollf(pfc, 16, (unsigned)(s + 1), ln);
      const f16* aph = (const f16*)p_hi + (size_t)slot_w * SLOT + (size_t)(rb + cl) * NH + qd * 8;
      const f16* apl = (const f16*)p_lo + (size_t)slot_w * SLOT + (size_t)(rb + cl) * NH + qd * 8;
#pragma unroll
      for (int kt = 0; kt < 16; ++kt) {
        f16x8 a0 = *(const f16x8*)(aph + kt * 32);
        f16x8 a1 = *(const f16x8*)(apl + kt * 32);
#pragma unroll
        for (int t4 = 0; t4 < 4; ++t4) {
          f16x8 bw = wx_[(t4 * 16 + kt) * 64 + ln];
          acc[t4]  = __builtin_amdgcn_mfma_f32_16x16x32_f16(a0, bw, acc[t4], 0, 0, 0);
          accL[t4] = __builtin_amdgcn_mfma_f32_16x16x32_f16(a1, bw, accL[t4], 0, 0, 0);
        }
      }
      f16* sh  = (f16*)(smem + 131072);    // 64 x 16 hi (2 KB)
      f16* slo = sh + 1024;                // 64 x 16 lo (2 KB)
      const bool hiH = (cl < 8);
#pragma unroll
      for (int e = 0; e < 4; ++e) {
        int r = wv * 16 + qd * 4 + e;
        int b = c * 64 + r;
        float po = 0.0f;
#pragma unroll
        for (int nh = 0; nh < 2; ++nh) {
          float v0 = acc[nh*2+0][e] + accL[nh*2+0][e] * LO + b1c0[nh];   // i / f
          float v1 = acc[nh*2+1][e] + accL[nh*2+1][e] * LO + b1c1[nh];   // g / o
          float w0 = __shfl_xor(v0, 8, 16);
          float w1 = __shfl_xor(v1, 8, 16);
          float gi = hiH ? v0 : w0;
          float gf = hiH ? w0 : v0;
          float gg = hiH ? v1 : w1;
          float go = hiH ? w1 : v1;
          float ii = sigm(gi), ff = sigm(gf), tg = tanhx(gg), oo = sigm(go);
          cst[nh][e] = ff * cst[nh][e] + ii * tg;
          float h = oo * tanhx(cst[nh][e]);
          int su = r * 16 + nh * 8 + (cl & 7);
          if (hiH) {
            sh[su] = (f16)h;
          } else {
            f16 hh = (f16)h;
            slo[su] = (f16)((h - (float)hh) * 1024.0f);
          }
          po += hiH ? wfv[nh] * h : 0.0f;
        }
#pragma unroll
        for (int m = 1; m < 16; m <<= 1) po += __shfl_xor(po, m, 16);
        if (cl == 0)
          atomicAdd(part8 + (size_t)(sl & 7) * (NB * NT_) + (size_t)b * NT_ + s, po);
      }
      __syncthreads();
      // coop WT store: 64 rows x 16 units x {hi,lo}, 8B pieces
      {
        unsigned short* bh = q_hi + (size_t)slot_w * SLOT;
        unsigned short* bl = q_lo + (size_t)slot_w * SLOT;
        for (int i = tid; i < 512; i += 256) {
          int strm = i >> 8, id2 = i & 255, r = id2 >> 2, j = id2 & 3;
          const f16* src = (strm ? slo : sh) + r * 16 + j * 4;
          unsigned short* dst = (strm ? bl : bh) + (size_t)(c * 64 + r) * NH + sl * 16 + j * 4;
          st8(dst, *(const u64*)src);
        }
      }
      __syncthreads();
      if (tid == 0)
        __hip_atomic_store(qfc + sl, (unsigned)(s + 1),
                           __ATOMIC_RELAXED, __HIP_MEMORY_SCOPE_AGENT);
    }
  }
}

// ---------------------------------------------------------------------------
extern "C" void kernel_launch(void* const* d_in, const int* in_sizes, int n_in,
                              void* d_out, int out_size, void* d_ws, size_t ws_size,
                              hipStream_t stream) {
  (void)in_sizes; (void)n_in; (void)out_size; (void)ws_size;
  const float* inp = (const float*)d_in[0];
  const float* Wx0 = (const float*)d_in[1];
  const float* Wh0 = (const float*)d_in[2];
  const float* b0  = (const float*)d_in[3];
  const float* Wx1 = (const float*)d_in[4];
  const float* Wh1 = (const float*)d_in[5];
  const float* b1  = (const float*)d_in[6];
  const float* Wf  = (const float*)d_in[7];
  const float* bf  = (const float*)d_in[8];

  const size_t MB = 1u << 20;
  const size_t OFF_W    = 0;                 // 6 MiB tiled fp16 weights
  const size_t OFF_XT   = 6 * MB;            // 1 MiB
  const size_t OFF_PHI  = 7 * MB;            // 4 MiB (RING x 256 KB)
  const size_t OFF_PLO  = 11 * MB;
  const size_t OFF_QHI  = 15 * MB;
  const size_t OFF_QLO  = 19 * MB;
  const size_t OFF_PART = 23 * MB;           // 8 MiB
  const size_t OFF_CTR  = 31 * MB;           // flags: pf 512 B + qf 512 B

  char* ws = (char*)d_ws;
  f16* wsl = (f16*)(ws + OFF_W);
  float* xT = (float*)(ws + OFF_XT);
  unsigned short* phi = (unsigned short*)(ws + OFF_PHI);
  unsigned short* plo = (unsigned short*)(ws + OFF_PLO);
  unsigned short* qhi = (unsigned short*)(ws + OFF_QHI);
  unsigned short* qlo = (unsigned short*)(ws + OFF_QLO);
  float* part8 = (float*)(ws + OFF_PART);
  unsigned int* pfl = (unsigned int*)(ws + OFF_CTR);
  unsigned int* qfl = pfl + 128;
  float* out = (float*)d_out;

  hipFuncSetAttribute((const void*)lstm_main,
                      hipFuncAttributeMaxDynamicSharedMemorySize, 139264);

  // zero rings + partials + flags (contiguous)
  hipMemsetAsync(ws + OFF_PHI, 0, (OFF_CTR + 1024) - OFF_PHI, stream);

  prep_xT<<<1024, 256, 0, stream>>>(inp, xT);
  prep_w<<<12288, 256, 0, stream>>>(Wh0, Wx1, Wh1, wsl);

  lstm_main<<<256, 256, 139264, stream>>>(xT, wsl, Wx0, b0, b1, Wf,
                                          phi, plo, qhi, qlo, pfl, qfl, part8);

  reduce_out<<<1024, 256, 0, stream>>>(part8, bf, out);
}